// Round 2
// baseline (336.623 us; speedup 1.0000x reference)
//
#include <hip/hip_runtime.h>

// MHSA: B=2, S=2048, D=1024, H=16, HD=64.  All matmuls bf16 MFMA, fp32 accum.

typedef __bf16 bf16x8 __attribute__((ext_vector_type(8)));
typedef float f32x4 __attribute__((ext_vector_type(4)));
typedef float f32x16 __attribute__((ext_vector_type(16)));

#define AS1 __attribute__((address_space(1)))
#define AS3 __attribute__((address_space(3)))

__device__ __forceinline__ ushort f2bf(float f) {
  unsigned u = __builtin_bit_cast(unsigned, f);
  u += 0x7fffu + ((u >> 16) & 1u);
  return (ushort)(u >> 16);
}

__device__ __forceinline__ float bf2f(ushort u) {
  return __builtin_bit_cast(float, (unsigned)u << 16);
}

__device__ __forceinline__ unsigned cvt_pk_bf16(float lo, float hi) {
  unsigned r;
  asm("v_cvt_pk_bf16_f32 %0, %1, %2" : "=v"(r) : "v"(lo), "v"(hi));
  return r;  // lo -> [15:0], hi -> [31:16]
}

__device__ __forceinline__ bf16x8 ld16(const ushort* p) {
  return __builtin_bit_cast(bf16x8, *(const uint4*)p);
}

__device__ __forceinline__ void gload16(const ushort* g, ushort* l) {
  __builtin_amdgcn_global_load_lds((const AS1 void*)g, (AS3 void*)l, 16, 0, 0);
}

#define MFMA32(a, b, c) __builtin_amdgcn_mfma_f32_32x32x16_bf16(a, b, c, 0, 0, 0)

// ---------------- cast f32 -> bf16 (vectorized) ----------------
__global__ void cast_bf16(const float4* __restrict__ in, ushort4* __restrict__ out, int n4) {
  int stride = gridDim.x * blockDim.x;
  for (int i = blockIdx.x * blockDim.x + threadIdx.x; i < n4; i += stride) {
    float4 v = in[i];
    ushort4 r;
    r.x = f2bf(v.x); r.y = f2bf(v.y); r.z = f2bf(v.z); r.w = f2bf(v.w);
    out[i] = r;
  }
}

// 4 weight matrices (each 1024x1024 f32) -> one contiguous bf16 buffer.
__global__ void cast4_bf16(const float4* __restrict__ a, const float4* __restrict__ b,
                           const float4* __restrict__ c, const float4* __restrict__ d,
                           ushort4* __restrict__ out) {
  const int n4each = 262144;  // 2^18
  int stride = gridDim.x * blockDim.x;
  for (int i = blockIdx.x * blockDim.x + threadIdx.x; i < 4 * n4each; i += stride) {
    int seg = i >> 18, off = i & (n4each - 1);
    const float4* s = seg == 0 ? a : seg == 1 ? b : seg == 2 ? c : d;
    float4 v = s[off];
    ushort4 r;
    r.x = f2bf(v.x); r.y = f2bf(v.y); r.z = f2bf(v.z); r.w = f2bf(v.w);
    out[i] = r;
  }
}

// ---------------- NT GEMM: C[m][n] = sum_k A[m][k]*B[n][k] ----------------
// 128x128 tile, BK=64, 4 waves (2x2), 16x16x32 bf16 MFMA, XOR-swizzled LDS.
template <bool F32OUT>
__global__ __launch_bounds__(256) void gemm_nt(const ushort* __restrict__ A,
                                               const ushort* __restrict__ B,
                                               void* __restrict__ Cv,
                                               int M, int N, int K) {
  __shared__ ushort As[128 * 64];
  __shared__ ushort Bs[128 * 64];
  const int tid = threadIdx.x;
  const int lane = tid & 63;
  const int wave = tid >> 6;
  const int r15 = lane & 15, hi = lane >> 4;
  const int bm = blockIdx.y * 128, bn = blockIdx.x * 128;
  const int wm = (wave >> 1) * 64, wn = (wave & 1) * 64;

  f32x4 acc[4][4] = {};

  const int KT = K >> 6;
  for (int kt = 0; kt < KT; ++kt) {
#pragma unroll
    for (int i = 0; i < 4; ++i) {
      int c = i * 256 + tid;          // 1024 chunks of 16B per matrix
      int row = c >> 3, slot = c & 7;
      int coff = kt * 64 + ((((slot * 16) ^ ((row & 7) << 4))) >> 1);  // ushort offset
      gload16(A + (size_t)(bm + row) * K + coff, As + c * 8);
      gload16(B + (size_t)(bn + row) * K + coff, Bs + c * 8);
    }
    __syncthreads();
#pragma unroll
    for (int kc = 0; kc < 2; ++kc) {
      bf16x8 af[4], bfr[4];
#pragma unroll
      for (int mi = 0; mi < 4; ++mi) {
        int ra = wm + mi * 16 + r15;
        af[mi] = ld16(As + ra * 64 + ((kc * 32 + hi * 8) ^ ((ra & 7) << 3)));
      }
#pragma unroll
      for (int nj = 0; nj < 4; ++nj) {
        int rb = wn + nj * 16 + r15;
        bfr[nj] = ld16(Bs + rb * 64 + ((kc * 32 + hi * 8) ^ ((rb & 7) << 3)));
      }
#pragma unroll
      for (int mi = 0; mi < 4; ++mi)
#pragma unroll
        for (int nj = 0; nj < 4; ++nj)
          acc[mi][nj] = __builtin_amdgcn_mfma_f32_16x16x32_bf16(af[mi], bfr[nj], acc[mi][nj], 0, 0, 0);
    }
    __syncthreads();
  }

#pragma unroll
  for (int mi = 0; mi < 4; ++mi)
#pragma unroll
    for (int nj = 0; nj < 4; ++nj) {
      int row = bm + wm + mi * 16 + hi * 4;
      int col = bn + wn + nj * 16 + r15;
#pragma unroll
      for (int j = 0; j < 4; ++j) {
        if (F32OUT)
          ((float*)Cv)[(size_t)(row + j) * N + col] = acc[mi][nj][j];
        else
          ((ushort*)Cv)[(size_t)(row + j) * N + col] = f2bf(acc[mi][nj][j]);
      }
    }
}

// ---------------- causal flash attention (swapped 32x32 MFMA, pipelined) ----
// QKV fused [B,S,3072]: Q at col 0, K at +1024, V at +2048.
// grid = (bh=32, y=32); block = 512 = 8 waves.  KVBLK = 32.
// y -> (qt, ks): j=y&7, i=y>>3; qt = i&1 ? 15-j : j; ks = i>>1.
//   (CU round-robin set {y,y+8,y+16,y+24} => qt {j,15-j,j,15-j}: constant
//    34 tile-units per CU.)
// Block ks handles kv tiles-of-32 [ks*2*(qt+1), (ks+1)*2*(qt+1)), split
// in-block into 2 streams (kh=wave>>2) of exactly qt+1 tiles each.
// K/V LDS: pair-combined [2 buf][64 rows][64] (rows/slots 0-31 = stream 0,
// 32-63 = stream 1) -> same verified conflict-free swizzles as KVBLK=64.
// Epilogue: in-block 2-way merge, then NORMALIZED partial O (bf16) + (m,l)
// (f32) to global; attn_combine merges the two ks blocks.
__global__ __launch_bounds__(512, 8) void attn_fwd(const ushort* __restrict__ QKV,
                                                   ushort* __restrict__ PartO,
                                                   float* __restrict__ Mp,
                                                   float* __restrict__ Lp) {
  __shared__ __align__(16) ushort lds[17408];  // Ks[2][4096] | Vs[2][4096] | ml(2KB)
  ushort* Ks0 = lds;                       // [2 buf][64 kv][64 d] swizzled
  ushort* Vs0 = lds + 8192;                // [2 buf][64 d][64 kv-slot] swizzled
  float* mlsh = (float*)(lds + 16384);     // 256 floats used
  float* osh = (float*)lds;                // 8192 f32 = 32KB (merge scratch)

  const int tid = threadIdx.x, lane = tid & 63, wave = tid >> 6;
  const int l31 = lane & 31, hi = lane >> 5;
  const int kh = wave >> 2;          // kv stream: 0 = lower half, 1 = upper
  const int hw = wave & 3;           // q sub-tile within block
  const int bh = blockIdx.x;
  const int y = blockIdx.y;
  const int jj = y & 7, iq = y >> 3;
  const int qt = (iq & 1) ? (15 - jj) : jj;
  const int ks = iq >> 1;            // which kv half-range (cross-block split)
  const int nh = qt + 1;             // tiles-of-32 per stream
  const int koff = ks * 2 * nh;      // this block's first tile-of-32
  const size_t base = (size_t)(bh >> 4) * (2048 * 3072) + (bh & 15) * 64;
  const int qbase = qt * 128 + hw * 32;
  const int qrow = qbase + l31;      // this lane's q row (softmax owner)

  // Q fragments: Q[qrow][c*16 + hi*8 + 0..7], c = 0..3
  bf16x8 qf[4];
  {
    const ushort* qp = QKV + base + (size_t)qrow * 3072 + hi * 8;
#pragma unroll
    for (int c = 0; c < 4; ++c) qf[c] = ld16(qp + c * 16);
  }

  // K staging: thread stages 1 chunk of 16B. LDS row tid>>3 (0..63):
  // rows 0-31 = stream 0's tile, 32-63 = stream 1's.
  const int krow = tid >> 3, kslot = tid & 7;
  const int ksub = krow >> 5;
  const ushort* kg = QKV + base + 1024 +
                     (size_t)((koff + ksub * nh) * 32 + (krow & 31)) * 3072 +
                     ((((kslot * 16) ^ ((krow & 7) << 4))) >> 1);
  // V staging: wave w covers d chunk w*8; lane = kv-slot (bit5 = stream).
  const int vsub = lane >> 5;
  const ushort* vg = QKV + base + 2048 +
                     (size_t)((koff + vsub * nh) * 32 + (lane & 31)) * 3072 + wave * 8;

  f32x16 o0 = {}, o1 = {};          // O^T acc: col=q=l31, row=d (o1: d+32)
  float m_r = -3e38f, l_r = 0.f;
  const float Cc = 0.125f * 1.44269504f;   // 1/sqrt(64) * log2(e)

  // ---- prologue: stage tile 0 of both streams into buf 0 ----
  {
    gload16(kg, Ks0 + tid * 8);
    union { uint4 u; ushort s[8]; } uv;
    uv.u = *(const uint4*)vg;
#pragma unroll
    for (int j = 0; j < 8; ++j) {
      int d = wave * 8 + j;
      Vs0[d * 64 + (lane ^ ((d & 7) << 3))] = uv.s[j];
    }
  }
  __syncthreads();

  for (int t = 0; t < nh; ++t) {
    const int buf = t & 1;
    const bool pre = (t + 1 < nh);
    uint4 va;
    // ---- issue next tile's loads (hidden under this tile's compute) ----
    if (pre) {
      const size_t roff = (size_t)(t + 1) * (32 * 3072);
      gload16(kg + roff, Ks0 + (buf ^ 1) * 4096 + tid * 8);
      va = *(const uint4*)(vg + roff);
    }

    const int kvb = (koff + kh * nh + t) * 32;
    if (kvb <= qbase + 31) {   // wave-uniform: at least one unmasked (q,kv)
      // ---- S^T = K Q^T ----
      f32x16 s = {};
#pragma unroll
      for (int c = 0; c < 4; ++c) {
        int col = c * 16 + hi * 8;
        int r0 = kh * 32 + l31;
        bf16x8 k0 = ld16(Ks0 + buf * 4096 + r0 * 64 + (col ^ ((r0 & 7) << 3)));
        s = MFMA32(k0, qf[c], s);
      }

      // ---- causal mask (wave-uniform branch) ----
      if (kvb + 31 > qbase) {
#pragma unroll
        for (int r = 0; r < 16; ++r) {
          int kvl = (r & 3) + 8 * (r >> 2) + 4 * hi;
          if (kvb + kvl > qrow) s[r] = -3e38f;
        }
      }

      // ---- online softmax: lane pair (l, l^32) owns one q row ----
      float tm[8];
#pragma unroll
      for (int r = 0; r < 8; ++r) tm[r] = fmaxf(s[r], s[r + 8]);
#pragma unroll
      for (int off = 4; off > 0; off >>= 1)
#pragma unroll
        for (int r = 0; r < off; ++r) tm[r] = fmaxf(tm[r], tm[r + off]);
      float mx = fmaxf(tm[0], __shfl_xor(tm[0], 32));

      // defer-max: only rescale when max grew by > 44 (p bounded by 2^8)
      if (!__all(mx - m_r <= 44.0f)) {
        float mnew = fmaxf(m_r, mx);
        float sc = exp2f((m_r - mnew) * Cc);
        l_r *= sc;
#pragma unroll
        for (int r = 0; r < 16; ++r) { o0[r] *= sc; o1[r] *= sc; }
        m_r = mnew;
      }
      float mC = m_r * Cc;
      float p[16];
#pragma unroll
      for (int r = 0; r < 16; ++r) p[r] = exp2f(fmaf(s[r], Cc, -mC));
      float ts[8];
#pragma unroll
      for (int r = 0; r < 8; ++r) ts[r] = p[r] + p[r + 8];
#pragma unroll
      for (int off = 4; off > 0; off >>= 1)
#pragma unroll
        for (int r = 0; r < off; ++r) ts[r] += ts[r + off];
      l_r += ts[0] + __shfl_xor(ts[0], 32);

      // ---- P -> bf16 B-fragments (cvt_pk + in-register exchange) + PV ----
#pragma unroll
      for (int c = 0; c < 2; ++c) {
        const int o = c * 8;
        unsigned uA0 = cvt_pk_bf16(p[o + 0], p[o + 1]);
        unsigned uA1 = cvt_pk_bf16(p[o + 2], p[o + 3]);
        unsigned uB0 = cvt_pk_bf16(p[o + 4], p[o + 5]);
        unsigned uB1 = cvt_pk_bf16(p[o + 6], p[o + 7]);
        unsigned r0x = __shfl_xor(hi ? uA0 : uB0, 32);
        unsigned r1x = __shfl_xor(hi ? uA1 : uB1, 32);
        uint4 y4;
        y4.x = hi ? r0x : uA0;
        y4.y = hi ? r1x : uA1;
        y4.z = hi ? uB0 : r0x;
        y4.w = hi ? uB1 : r1x;
        bf16x8 pf = __builtin_bit_cast(bf16x8, y4);

        int col = kh * 32 + c * 16 + hi * 8;
        int d0r = l31, d1r = 32 + l31;
        bf16x8 v0 = ld16(Vs0 + buf * 4096 + d0r * 64 + (col ^ ((d0r & 7) << 3)));
        bf16x8 v1 = ld16(Vs0 + buf * 4096 + d1r * 64 + (col ^ ((d1r & 7) << 3)));
        o0 = MFMA32(v0, pf, o0);
        o1 = MFMA32(v1, pf, o1);
      }
    }

    // ---- late V write for next tile (vmcnt wait covered by compute) ----
    if (pre) {
      union { uint4 u; ushort s[8]; } uv;
      uv.u = va;
#pragma unroll
      for (int j = 0; j < 8; ++j) {
        int d = wave * 8 + j;
        Vs0[(buf ^ 1) * 4096 + d * 64 + (lane ^ ((d & 7) << 3))] = uv.s[j];
      }
    }
    __syncthreads();
  }

  // ---- in-block merge of the 2 streams (pair: wave hw, wave hw+4) ----
  if (kh) {
#pragma unroll
    for (int r = 0; r < 16; ++r) {
      osh[(hw * 32 + r) * 64 + lane] = o0[r];
      osh[(hw * 32 + 16 + r) * 64 + lane] = o1[r];
    }
    if (lane < 32) {
      mlsh[hw * 32 + lane] = m_r;
      mlsh[128 + hw * 32 + lane] = l_r;
    }
  }
  __syncthreads();
  const int pidx = (ks << 9) | (bh << 4) | qt;
  if (!kh) {
    float m_hi = mlsh[hw * 32 + l31];
    float l_hi = mlsh[128 + hw * 32 + l31];
    float M = fmaxf(m_r, m_hi);
    float ea = exp2f((m_r - M) * Cc);     // safe: both >= -3e38 (no inf-inf)
    float eb = exp2f((m_hi - M) * Cc);
    float lm = fmaf(l_r, ea, l_hi * eb);
    float linv = lm > 0.f ? 1.0f / lm : 0.f;
    float fa = ea * linv, fb = eb * linv;
#pragma unroll
    for (int r = 0; r < 16; ++r) {
      o0[r] = fmaf(o0[r], fa, osh[(hw * 32 + r) * 64 + lane] * fb);
      o1[r] = fmaf(o1[r], fa, osh[(hw * 32 + 16 + r) * 64 + lane] * fb);
    }
    if (lane < 32) {
      Mp[pidx * 128 + hw * 32 + l31] = M;
      Lp[pidx * 128 + hw * 32 + l31] = lm;
    }
  }
  __syncthreads();          // osh reads done before sm overwrite
  if (!kh) {
    ushort* sm = lds;       // [64 d][128 q] bf16, normalized partial
    int q = hw * 32 + l31;
#pragma unroll
    for (int r = 0; r < 16; ++r) {
      int d = (r & 3) + 8 * (r >> 2) + 4 * hi;
      sm[d * 128 + q] = f2bf(o0[r]);
      sm[(d + 32) * 128 + q] = f2bf(o1[r]);
    }
  }
  __syncthreads();
  // ---- coalesced partial store: 1024 chunks of 16B ----
#pragma unroll
  for (int i = 0; i < 2; ++i) {
    int idx = i * 512 + tid;
    *(uint4*)(PartO + (size_t)pidx * 8192 + idx * 8) = *(const uint4*)(lds + idx * 8);
  }
}

// ---------------- combine the 2 kv-half blocks per (qt, bh) ----------------
__global__ __launch_bounds__(256) void attn_combine(const ushort* __restrict__ PartO,
                                                    const float* __restrict__ Mp,
                                                    const float* __restrict__ Lp,
                                                    ushort* __restrict__ Ob) {
  __shared__ __align__(16) ushort s0[8192];   // [64 d][128 q]
  __shared__ __align__(16) ushort s1[8192];
  const int tid = threadIdx.x;
  const int qt = blockIdx.x, bh = blockIdx.y;
  const int p0 = (bh << 4) | qt, p1 = p0 | 512;
#pragma unroll
  for (int i = 0; i < 4; ++i) {
    int idx = i * 256 + tid;
    *(uint4*)(s0 + idx * 8) = *(const uint4*)(PartO + (size_t)p0 * 8192 + idx * 8);
    *(uint4*)(s1 + idx * 8) = *(const uint4*)(PartO + (size_t)p1 * 8192 + idx * 8);
  }
  __syncthreads();
  const float Cc = 0.125f * 1.44269504f;
  const int q = tid >> 1, d0 = (tid & 1) * 32;
  float m0 = Mp[p0 * 128 + q], l0 = Lp[p0 * 128 + q];
  float m1 = Mp[p1 * 128 + q], l1 = Lp[p1 * 128 + q];
  float M = fmaxf(m0, m1);
  float w0 = l0 * exp2f((m0 - M) * Cc);
  float w1 = l1 * exp2f((m1 - M) * Cc);
  float rn = 1.0f / (w0 + w1);          // w0 > 0 always (lower kv half live)
  float a = w0 * rn, b = w1 * rn;
  ushort tmp[32];
#pragma unroll
  for (int j = 0; j < 32; ++j) {
    int d = d0 + j;
    tmp[j] = f2bf(fmaf(a, bf2f(s0[d * 128 + q]), b * bf2f(s1[d * 128 + q])));
  }
  const size_t obase = (size_t)(bh >> 4) * (2048 * 1024) + (bh & 15) * 64;
  ushort* op = Ob + obase + (size_t)(qt * 128 + q) * 1024 + d0;
#pragma unroll
  for (int i = 0; i < 4; ++i) *(uint4*)(op + i * 8) = *(const uint4*)(tmp + i * 8);
}

// ---------------- launcher ----------------
extern "C" void kernel_launch(void* const* d_in, const int* in_sizes, int n_in,
                              void* d_out, int out_size, void* d_ws, size_t ws_size,
                              hipStream_t stream) {
  (void)in_sizes; (void)n_in; (void)out_size; (void)ws_size;
  const float* x = (const float*)d_in[0];
  const float* qw = (const float*)d_in[1];
  const float* kw = (const float*)d_in[2];
  const float* vw = (const float*)d_in[3];
  const float* ow = (const float*)d_in[4];
  float* out = (float*)d_out;

  const int NT = 4096;   // B*S tokens
  const int D = 1024;

  ushort* xb    = (ushort*)d_ws;               // [4096][1024]
  ushort* wqkv  = xb + (size_t)NT * D;         // [3072][1024] (q,k,v rows)
  ushort* wob   = wqkv + (size_t)3 * D * D;    // [1024][1024]
  ushort* QKVb  = wob + (size_t)D * D;         // [4096][3072]
  ushort* Ob    = QKVb + (size_t)NT * 3 * D;   // [4096][1024]
  ushort* PartO = Ob + (size_t)NT * D;         // [1024][64][128] bf16
  float*  Mp    = (float*)(PartO + (size_t)1024 * 8192);  // [1024][128]
  float*  Lp    = Mp + 1024 * 128;                        // [1024][128]

  // casts (q,k,v,o weights contiguous: wqkv then wob)
  cast_bf16<<<2048, 256, 0, stream>>>((const float4*)x, (ushort4*)xb, NT * D / 4);
  cast4_bf16<<<1024, 256, 0, stream>>>((const float4*)qw, (const float4*)kw,
                                       (const float4*)vw, (const float4*)ow,
                                       (ushort4*)wqkv);

  // fused QKV projection: [4096,1024] x [3072,1024]^T -> [4096,3072]
  gemm_nt<false><<<dim3(3 * D / 128, NT / 128), 256, 0, stream>>>(xb, wqkv, QKVb, NT, 3 * D, D);

  // causal flash attention: 1024 blocks (2-way kv split across blocks,
  // 2-way in-block), then combine
  attn_fwd<<<dim3(32, 32), 512, 0, stream>>>(QKVb, PartO, Mp, Lp);
  attn_combine<<<dim3(16, 32), 256, 0, stream>>>(PartO, Mp, Lp, Ob);

  // output projection (f32 out)
  gemm_nt<true><<<dim3(D / 128, NT / 128), 256, 0, stream>>>(Ob, wob, out, NT, D, D);
}

// Round 3
// 124.877 us; speedup vs baseline: 2.6956x; 2.6956x over previous
//
#include <hip/hip_runtime.h>

// MHSA: B=2, S=2048, D=1024, H=16, HD=64.  All matmuls bf16 MFMA, fp32 accum.

typedef __bf16 bf16x8 __attribute__((ext_vector_type(8)));
typedef float f32x4 __attribute__((ext_vector_type(4)));
typedef float f32x16 __attribute__((ext_vector_type(16)));

#define AS1 __attribute__((address_space(1)))
#define AS3 __attribute__((address_space(3)))

__device__ __forceinline__ ushort f2bf(float f) {
  unsigned u = __builtin_bit_cast(unsigned, f);
  u += 0x7fffu + ((u >> 16) & 1u);
  return (ushort)(u >> 16);
}

__device__ __forceinline__ float bf2f(ushort u) {
  return __builtin_bit_cast(float, (unsigned)u << 16);
}

__device__ __forceinline__ unsigned cvt_pk_bf16(float lo, float hi) {
  unsigned r;
  asm("v_cvt_pk_bf16_f32 %0, %1, %2" : "=v"(r) : "v"(lo), "v"(hi));
  return r;  // lo -> [15:0], hi -> [31:16]
}

__device__ __forceinline__ bf16x8 ld16(const ushort* p) {
  return __builtin_bit_cast(bf16x8, *(const uint4*)p);
}

__device__ __forceinline__ void gload16(const ushort* g, ushort* l) {
  __builtin_amdgcn_global_load_lds((const AS1 void*)g, (AS3 void*)l, 16, 0, 0);
}

#define MFMA32(a, b, c) __builtin_amdgcn_mfma_f32_32x32x16_bf16(a, b, c, 0, 0, 0)

// ---------------- cast f32 -> bf16 (vectorized) ----------------
__global__ void cast_bf16(const float4* __restrict__ in, ushort4* __restrict__ out, int n4) {
  int stride = gridDim.x * blockDim.x;
  for (int i = blockIdx.x * blockDim.x + threadIdx.x; i < n4; i += stride) {
    float4 v = in[i];
    ushort4 r;
    r.x = f2bf(v.x); r.y = f2bf(v.y); r.z = f2bf(v.z); r.w = f2bf(v.w);
    out[i] = r;
  }
}

// 4 weight matrices (each 1024x1024 f32) -> one contiguous bf16 buffer.
__global__ void cast4_bf16(const float4* __restrict__ a, const float4* __restrict__ b,
                           const float4* __restrict__ c, const float4* __restrict__ d,
                           ushort4* __restrict__ out) {
  const int n4each = 262144;  // 2^18
  int stride = gridDim.x * blockDim.x;
  for (int i = blockIdx.x * blockDim.x + threadIdx.x; i < 4 * n4each; i += stride) {
    int seg = i >> 18, off = i & (n4each - 1);
    const float4* s = seg == 0 ? a : seg == 1 ? b : seg == 2 ? c : d;
    float4 v = s[off];
    ushort4 r;
    r.x = f2bf(v.x); r.y = f2bf(v.y); r.z = f2bf(v.z); r.w = f2bf(v.w);
    out[i] = r;
  }
}

// ---------------- NT GEMM: C[m][n] = sum_k A[m][k]*B[n][k] ----------------
// 128x128 tile, BK=64, 4 waves (2x2), 16x16x32 bf16 MFMA, XOR-swizzled LDS.
template <bool F32OUT>
__global__ __launch_bounds__(256) void gemm_nt(const ushort* __restrict__ A,
                                               const ushort* __restrict__ B,
                                               void* __restrict__ Cv,
                                               int M, int N, int K) {
  __shared__ ushort As[128 * 64];
  __shared__ ushort Bs[128 * 64];
  const int tid = threadIdx.x;
  const int lane = tid & 63;
  const int wave = tid >> 6;
  const int r15 = lane & 15, hi = lane >> 4;
  const int bm = blockIdx.y * 128, bn = blockIdx.x * 128;
  const int wm = (wave >> 1) * 64, wn = (wave & 1) * 64;

  f32x4 acc[4][4] = {};

  const int KT = K >> 6;
  for (int kt = 0; kt < KT; ++kt) {
#pragma unroll
    for (int i = 0; i < 4; ++i) {
      int c = i * 256 + tid;          // 1024 chunks of 16B per matrix
      int row = c >> 3, slot = c & 7;
      int coff = kt * 64 + ((((slot * 16) ^ ((row & 7) << 4))) >> 1);  // ushort offset
      gload16(A + (size_t)(bm + row) * K + coff, As + c * 8);
      gload16(B + (size_t)(bn + row) * K + coff, Bs + c * 8);
    }
    __syncthreads();
#pragma unroll
    for (int kc = 0; kc < 2; ++kc) {
      bf16x8 af[4], bfr[4];
#pragma unroll
      for (int mi = 0; mi < 4; ++mi) {
        int ra = wm + mi * 16 + r15;
        af[mi] = ld16(As + ra * 64 + ((kc * 32 + hi * 8) ^ ((ra & 7) << 3)));
      }
#pragma unroll
      for (int nj = 0; nj < 4; ++nj) {
        int rb = wn + nj * 16 + r15;
        bfr[nj] = ld16(Bs + rb * 64 + ((kc * 32 + hi * 8) ^ ((rb & 7) << 3)));
      }
#pragma unroll
      for (int mi = 0; mi < 4; ++mi)
#pragma unroll
        for (int nj = 0; nj < 4; ++nj)
          acc[mi][nj] = __builtin_amdgcn_mfma_f32_16x16x32_bf16(af[mi], bfr[nj], acc[mi][nj], 0, 0, 0);
    }
    __syncthreads();
  }

#pragma unroll
  for (int mi = 0; mi < 4; ++mi)
#pragma unroll
    for (int nj = 0; nj < 4; ++nj) {
      int row = bm + wm + mi * 16 + hi * 4;
      int col = bn + wn + nj * 16 + r15;
#pragma unroll
      for (int j = 0; j < 4; ++j) {
        if (F32OUT)
          ((float*)Cv)[(size_t)(row + j) * N + col] = acc[mi][nj][j];
        else
          ((ushort*)Cv)[(size_t)(row + j) * N + col] = f2bf(acc[mi][nj][j]);
      }
    }
}

// ---------------- causal flash attention (swapped 32x32 MFMA, pipelined) ----
// QKV fused [B,S,3072]: Q at col 0, K at +1024, V at +2048.
// grid = (bh=32, y=32); block = 512 = 8 waves.  KVBLK = 32.
// y -> (qt, ks): j=y&7, i=y>>3; qt = i&1 ? 15-j : j; ks = i>>1.
// Block ks handles kv tiles-of-32 [ks*2*(qt+1), (ks+1)*2*(qt+1)), split
// in-block into 2 streams (kh=wave>>2) of exactly qt+1 tiles each.
// K/V LDS: pair-combined [2 buf][64 rows][64] (rows/slots 0-31 = stream 0,
// 32-63 = stream 1) -> same verified conflict-free swizzles as KVBLK=64.
// Epilogue: in-block 2-way merge, then NORMALIZED partial O (bf16) + (m,l)
// (f32) to global; attn_combine merges the two ks blocks.
// NOTE launch_bounds (512,4): (512,8) caps unified regs at 64 -> the 32-reg
// O-accumulator forces mass scratch spill (R2: 1.1 GB spill traffic).
__global__ __launch_bounds__(512, 4) void attn_fwd(const ushort* __restrict__ QKV,
                                                   ushort* __restrict__ PartO,
                                                   float* __restrict__ Mp,
                                                   float* __restrict__ Lp) {
  __shared__ __align__(16) ushort lds[17408];  // Ks[2][4096] | Vs[2][4096] | ml(2KB)
  ushort* Ks0 = lds;                       // [2 buf][64 kv][64 d] swizzled
  ushort* Vs0 = lds + 8192;                // [2 buf][64 d][64 kv-slot] swizzled
  float* mlsh = (float*)(lds + 16384);     // 256 floats used
  float* osh = (float*)lds;                // 8192 f32 = 32KB (merge scratch)

  const int tid = threadIdx.x, lane = tid & 63, wave = tid >> 6;
  const int l31 = lane & 31, hi = lane >> 5;
  const int kh = wave >> 2;          // kv stream: 0 = lower half, 1 = upper
  const int hw = wave & 3;           // q sub-tile within block
  const int bh = blockIdx.x;
  const int y = blockIdx.y;
  const int jj = y & 7, iq = y >> 3;
  const int qt = (iq & 1) ? (15 - jj) : jj;
  const int ks = iq >> 1;            // which kv half-range (cross-block split)
  const int nh = qt + 1;             // tiles-of-32 per stream
  const int koff = ks * 2 * nh;      // this block's first tile-of-32
  const size_t base = (size_t)(bh >> 4) * (2048 * 3072) + (bh & 15) * 64;
  const int qbase = qt * 128 + hw * 32;
  const int qrow = qbase + l31;      // this lane's q row (softmax owner)

  // Q fragments: Q[qrow][c*16 + hi*8 + 0..7], c = 0..3
  bf16x8 qf[4];
  {
    const ushort* qp = QKV + base + (size_t)qrow * 3072 + hi * 8;
#pragma unroll
    for (int c = 0; c < 4; ++c) qf[c] = ld16(qp + c * 16);
  }

  // K staging: thread stages 1 chunk of 16B. LDS row tid>>3 (0..63):
  // rows 0-31 = stream 0's tile, 32-63 = stream 1's.
  const int krow = tid >> 3, kslot = tid & 7;
  const int ksub = krow >> 5;
  const ushort* kg = QKV + base + 1024 +
                     (size_t)((koff + ksub * nh) * 32 + (krow & 31)) * 3072 +
                     ((((kslot * 16) ^ ((krow & 7) << 4))) >> 1);
  // V staging: wave w covers d chunk w*8; lane = kv-slot (bit5 = stream).
  const int vsub = lane >> 5;
  const ushort* vg = QKV + base + 2048 +
                     (size_t)((koff + vsub * nh) * 32 + (lane & 31)) * 3072 + wave * 8;

  f32x16 o0 = {}, o1 = {};          // O^T acc: col=q=l31, row=d (o1: d+32)
  float m_r = -3e38f, l_r = 0.f;
  const float Cc = 0.125f * 1.44269504f;   // 1/sqrt(64) * log2(e)

  // ---- prologue: stage tile 0 of both streams into buf 0 ----
  {
    gload16(kg, Ks0 + tid * 8);
    union { uint4 u; ushort s[8]; } uv;
    uv.u = *(const uint4*)vg;
#pragma unroll
    for (int j = 0; j < 8; ++j) {
      int d = wave * 8 + j;
      Vs0[d * 64 + (lane ^ ((d & 7) << 3))] = uv.s[j];
    }
  }
  __syncthreads();

  for (int t = 0; t < nh; ++t) {
    const int buf = t & 1;
    const bool pre = (t + 1 < nh);
    uint4 va;
    // ---- issue next tile's loads (hidden under this tile's compute) ----
    if (pre) {
      const size_t roff = (size_t)(t + 1) * (32 * 3072);
      gload16(kg + roff, Ks0 + (buf ^ 1) * 4096 + tid * 8);
      va = *(const uint4*)(vg + roff);
    }

    const int kvb = (koff + kh * nh + t) * 32;
    if (kvb <= qbase + 31) {   // wave-uniform: at least one unmasked (q,kv)
      // ---- S^T = K Q^T ----
      f32x16 s = {};
#pragma unroll
      for (int c = 0; c < 4; ++c) {
        int col = c * 16 + hi * 8;
        int r0 = kh * 32 + l31;
        bf16x8 k0 = ld16(Ks0 + buf * 4096 + r0 * 64 + (col ^ ((r0 & 7) << 3)));
        s = MFMA32(k0, qf[c], s);
      }

      // ---- causal mask (wave-uniform branch) ----
      if (kvb + 31 > qbase) {
#pragma unroll
        for (int r = 0; r < 16; ++r) {
          int kvl = (r & 3) + 8 * (r >> 2) + 4 * hi;
          if (kvb + kvl > qrow) s[r] = -3e38f;
        }
      }

      // ---- online softmax: lane pair (l, l^32) owns one q row ----
      float tm[8];
#pragma unroll
      for (int r = 0; r < 8; ++r) tm[r] = fmaxf(s[r], s[r + 8]);
#pragma unroll
      for (int off = 4; off > 0; off >>= 1)
#pragma unroll
        for (int r = 0; r < off; ++r) tm[r] = fmaxf(tm[r], tm[r + off]);
      float mx = fmaxf(tm[0], __shfl_xor(tm[0], 32));

      // defer-max: only rescale when max grew by > 44 (p bounded by 2^8)
      if (!__all(mx - m_r <= 44.0f)) {
        float mnew = fmaxf(m_r, mx);
        float sc = exp2f((m_r - mnew) * Cc);
        l_r *= sc;
#pragma unroll
        for (int r = 0; r < 16; ++r) { o0[r] *= sc; o1[r] *= sc; }
        m_r = mnew;
      }
      float mC = m_r * Cc;
      float p[16];
#pragma unroll
      for (int r = 0; r < 16; ++r) p[r] = exp2f(fmaf(s[r], Cc, -mC));
      float ts[8];
#pragma unroll
      for (int r = 0; r < 8; ++r) ts[r] = p[r] + p[r + 8];
#pragma unroll
      for (int off = 4; off > 0; off >>= 1)
#pragma unroll
        for (int r = 0; r < off; ++r) ts[r] += ts[r + off];
      l_r += ts[0] + __shfl_xor(ts[0], 32);

      // ---- P -> bf16 B-fragments (cvt_pk + in-register exchange) + PV ----
#pragma unroll
      for (int c = 0; c < 2; ++c) {
        const int o = c * 8;
        unsigned uA0 = cvt_pk_bf16(p[o + 0], p[o + 1]);
        unsigned uA1 = cvt_pk_bf16(p[o + 2], p[o + 3]);
        unsigned uB0 = cvt_pk_bf16(p[o + 4], p[o + 5]);
        unsigned uB1 = cvt_pk_bf16(p[o + 6], p[o + 7]);
        unsigned r0x = __shfl_xor(hi ? uA0 : uB0, 32);
        unsigned r1x = __shfl_xor(hi ? uA1 : uB1, 32);
        uint4 y4;
        y4.x = hi ? r0x : uA0;
        y4.y = hi ? r1x : uA1;
        y4.z = hi ? uB0 : r0x;
        y4.w = hi ? uB1 : r1x;
        bf16x8 pf = __builtin_bit_cast(bf16x8, y4);

        int col = kh * 32 + c * 16 + hi * 8;
        int d0r = l31, d1r = 32 + l31;
        bf16x8 v0 = ld16(Vs0 + buf * 4096 + d0r * 64 + (col ^ ((d0r & 7) << 3)));
        bf16x8 v1 = ld16(Vs0 + buf * 4096 + d1r * 64 + (col ^ ((d1r & 7) << 3)));
        o0 = MFMA32(v0, pf, o0);
        o1 = MFMA32(v1, pf, o1);
      }
    }

    // ---- late V write for next tile (vmcnt wait covered by compute) ----
    if (pre) {
      union { uint4 u; ushort s[8]; } uv;
      uv.u = va;
#pragma unroll
      for (int j = 0; j < 8; ++j) {
        int d = wave * 8 + j;
        Vs0[(buf ^ 1) * 4096 + d * 64 + (lane ^ ((d & 7) << 3))] = uv.s[j];
      }
    }
    __syncthreads();
  }

  // ---- in-block merge of the 2 streams (pair: wave hw, wave hw+4) ----
  if (kh) {
#pragma unroll
    for (int r = 0; r < 16; ++r) {
      osh[(hw * 32 + r) * 64 + lane] = o0[r];
      osh[(hw * 32 + 16 + r) * 64 + lane] = o1[r];
    }
    if (lane < 32) {
      mlsh[hw * 32 + lane] = m_r;
      mlsh[128 + hw * 32 + lane] = l_r;
    }
  }
  __syncthreads();
  const int pidx = (ks << 9) | (bh << 4) | qt;
  if (!kh) {
    float m_hi = mlsh[hw * 32 + l31];
    float l_hi = mlsh[128 + hw * 32 + l31];
    float M = fmaxf(m_r, m_hi);
    float ea = exp2f((m_r - M) * Cc);     // safe: both >= -3e38 (no inf-inf)
    float eb = exp2f((m_hi - M) * Cc);
    float lm = fmaf(l_r, ea, l_hi * eb);
    float linv = lm > 0.f ? 1.0f / lm : 0.f;
    float fa = ea * linv, fb = eb * linv;
#pragma unroll
    for (int r = 0; r < 16; ++r) {
      o0[r] = fmaf(o0[r], fa, osh[(hw * 32 + r) * 64 + lane] * fb);
      o1[r] = fmaf(o1[r], fa, osh[(hw * 32 + 16 + r) * 64 + lane] * fb);
    }
    if (lane < 32) {
      Mp[pidx * 128 + hw * 32 + l31] = M;
      Lp[pidx * 128 + hw * 32 + l31] = lm;
    }
  }
  __syncthreads();          // osh reads done before sm overwrite
  if (!kh) {
    ushort* sm = lds;       // [64 d][128 q] bf16, normalized partial
    int q = hw * 32 + l31;
#pragma unroll
    for (int r = 0; r < 16; ++r) {
      int d = (r & 3) + 8 * (r >> 2) + 4 * hi;
      sm[d * 128 + q] = f2bf(o0[r]);
      sm[(d + 32) * 128 + q] = f2bf(o1[r]);
    }
  }
  __syncthreads();
  // ---- coalesced partial store: 1024 chunks of 16B ----
#pragma unroll
  for (int i = 0; i < 2; ++i) {
    int idx = i * 512 + tid;
    *(uint4*)(PartO + (size_t)pidx * 8192 + idx * 8) = *(const uint4*)(lds + idx * 8);
  }
}

// ---------------- combine the 2 kv-half blocks per (qt, bh) ----------------
__global__ __launch_bounds__(256) void attn_combine(const ushort* __restrict__ PartO,
                                                    const float* __restrict__ Mp,
                                                    const float* __restrict__ Lp,
                                                    ushort* __restrict__ Ob) {
  __shared__ __align__(16) ushort s0[8192];   // [64 d][128 q]
  __shared__ __align__(16) ushort s1[8192];
  const int tid = threadIdx.x;
  const int qt = blockIdx.x, bh = blockIdx.y;
  const int p0 = (bh << 4) | qt, p1 = p0 | 512;
#pragma unroll
  for (int i = 0; i < 4; ++i) {
    int idx = i * 256 + tid;
    *(uint4*)(s0 + idx * 8) = *(const uint4*)(PartO + (size_t)p0 * 8192 + idx * 8);
    *(uint4*)(s1 + idx * 8) = *(const uint4*)(PartO + (size_t)p1 * 8192 + idx * 8);
  }
  __syncthreads();
  const float Cc = 0.125f * 1.44269504f;
  const int q = tid >> 1, d0 = (tid & 1) * 32;
  float m0 = Mp[p0 * 128 + q], l0 = Lp[p0 * 128 + q];
  float m1 = Mp[p1 * 128 + q], l1 = Lp[p1 * 128 + q];
  float M = fmaxf(m0, m1);
  float w0 = l0 * exp2f((m0 - M) * Cc);
  float w1 = l1 * exp2f((m1 - M) * Cc);
  float rn = 1.0f / (w0 + w1);          // w0 > 0 always (lower kv half live)
  float a = w0 * rn, b = w1 * rn;
  ushort tmp[32];
#pragma unroll
  for (int j = 0; j < 32; ++j) {
    int d = d0 + j;
    tmp[j] = f2bf(fmaf(a, bf2f(s0[d * 128 + q]), b * bf2f(s1[d * 128 + q])));
  }
  const size_t obase = (size_t)(bh >> 4) * (2048 * 1024) + (bh & 15) * 64;
  ushort* op = Ob + obase + (size_t)(qt * 128 + q) * 1024 + d0;
#pragma unroll
  for (int i = 0; i < 4; ++i) *(uint4*)(op + i * 8) = *(const uint4*)(tmp + i * 8);
}

// ---------------- launcher ----------------
extern "C" void kernel_launch(void* const* d_in, const int* in_sizes, int n_in,
                              void* d_out, int out_size, void* d_ws, size_t ws_size,
                              hipStream_t stream) {
  (void)in_sizes; (void)n_in; (void)out_size; (void)ws_size;
  const float* x = (const float*)d_in[0];
  const float* qw = (const float*)d_in[1];
  const float* kw = (const float*)d_in[2];
  const float* vw = (const float*)d_in[3];
  const float* ow = (const float*)d_in[4];
  float* out = (float*)d_out;

  const int NT = 4096;   // B*S tokens
  const int D = 1024;

  ushort* xb    = (ushort*)d_ws;               // [4096][1024]
  ushort* wqkv  = xb + (size_t)NT * D;         // [3072][1024] (q,k,v rows)
  ushort* wob   = wqkv + (size_t)3 * D * D;    // [1024][1024]
  ushort* QKVb  = wob + (size_t)D * D;         // [4096][3072]
  ushort* Ob    = QKVb + (size_t)NT * 3 * D;   // [4096][1024]
  ushort* PartO = Ob + (size_t)NT * D;         // [1024][64][128] bf16
  float*  Mp    = (float*)(PartO + (size_t)1024 * 8192);  // [1024][128]
  float*  Lp    = Mp + 1024 * 128;                        // [1024][128]

  // casts (q,k,v,o weights contiguous: wqkv then wob)
  cast_bf16<<<2048, 256, 0, stream>>>((const float4*)x, (ushort4*)xb, NT * D / 4);
  cast4_bf16<<<1024, 256, 0, stream>>>((const float4*)qw, (const float4*)kw,
                                       (const float4*)vw, (const float4*)ow,
                                       (ushort4*)wqkv);

  // fused QKV projection: [4096,1024] x [3072,1024]^T -> [4096,3072]
  gemm_nt<false><<<dim3(3 * D / 128, NT / 128), 256, 0, stream>>>(xb, wqkv, QKVb, NT, 3 * D, D);

  // causal flash attention: 1024 blocks (2-way kv split across blocks,
  // 2-way in-block), then combine
  attn_fwd<<<dim3(32, 32), 512, 0, stream>>>(QKVb, PartO, Mp, Lp);
  attn_combine<<<dim3(16, 32), 256, 0, stream>>>(PartO, Mp, Lp, Ob);

  // output projection (f32 out)
  gemm_nt<true><<<dim3(D / 128, NT / 128), 256, 0, stream>>>(Ob, wob, out, NT, D, D);
}